// Round 11
// baseline (290.840 us; speedup 1.0000x reference)
//
#include <hip/hip_runtime.h>

// ROI pooling 3D as one-hot MFMA GEMM (transposed): part[ch][seg] = sum_v feat[ch][v] * onehot[v][seg].
// R11: 4-tile super-tiles loaded as one 512B-contiguous burst per channel (8 back-to-back float4s,
// in registers, no LDS); blocks specialize 64 channels (pairs share a tile chunk) -> smaller acc,
// smaller partials. Counts fused (half-0 blocks, wave 0). No barriers, deterministic tree.
constexpr int CROP_D  = 91, CROP_H = 109, CROP_W = 91;
constexpr int FEAT_HW = 112 * 96;
constexpr int CSTRIDE = 96 * 112 * 96;                // per-(b,c) elements
constexpr int SPP     = 82;                           // super-tiles per plane (81x4 + 1x3 tiles)
constexpr int NST     = CROP_D * SPP;                 // 7462
constexpr int NCH     = 512;                          // tile-chunks
constexpr int GRID    = NCH * 2;                      // 1024 blocks (x2 channel halves)
constexpr int PSEG    = 96;                           // 95 segs + trash col
constexpr int ROWS    = 65;                           // 64 local ch + counts row
constexpr int BIN_SZ  = ROWS * PSEG;                  // 6240 floats per partial
constexpr int NCHUNK  = 16;                           // 8 tile-groups x 2 halves
constexpr int OUT_N   = 2 * 94 * 64;
constexpr size_t PART2_OFF = (size_t)GRID * BIN_SZ * sizeof(float);
constexpr size_t WS_NEED   = PART2_OFF + (size_t)NCHUNK * BIN_SZ * sizeof(float);

typedef __attribute__((ext_vector_type(8))) short bf16x8;
typedef __attribute__((ext_vector_type(4))) float f32x4;

__device__ inline unsigned int rne2(float a, float b) {   // 2x fp32 -> packed bf16 (RNE)
    unsigned int x = __float_as_uint(a), y = __float_as_uint(b);
    x = (x + 0x7FFFu + ((x >> 16) & 1u)) >> 16;
    y = (y + 0x7FFFu + ((y >> 16) & 1u)) & 0xFFFF0000u;
    return x | y;
}

__global__ __launch_bounds__(256) void zero_part(float* __restrict__ p)   // atomic-fallback only
{
    const int i = blockIdx.x * 256 + threadIdx.x;
    if (i < 2 * BIN_SZ) p[i] = 0.0f;
}

__global__ __launch_bounds__(256, 4) void seg_mfma(const float* __restrict__ feat,
                                                   const int*   __restrict__ atlas,
                                                   float* __restrict__ part,
                                                   int use_atomic)
{
    const int tid = threadIdx.x, wv = tid >> 6, lane = tid & 63;
    const int l15 = lane & 15, lq = lane >> 4;
    const int bx  = blockIdx.x, c = bx >> 1, half = bx & 1;

    f32x4 acc[6], accc[6];                              // 24 + 24 VGPR
    #pragma unroll
    for (int s = 0; s < 6; ++s) {
        acc[s]  = (f32x4){0.f, 0.f, 0.f, 0.f};
        accc[s] = (f32x4){0.f, 0.f, 0.f, 0.f};
    }
    union { bf16x8 v; unsigned int u[4]; } ONES;
    ONES.u[0] = ONES.u[1] = ONES.u[2] = ONES.u[3] = 0x3F803F80u;

    // Contiguous balanced chunk of super-tiles per block pair.
    const int base = NST / NCH, rem = NST % NCH;        // 14, 294
    const int st0  = c * base + (c < rem ? c : rem);
    const int st1  = st0 + base + (c < rem ? 1 : 0);

    const float* fbase = feat + (size_t)(half * 64 + wv * 16 + l15) * CSTRIDE;
    const bool do_cnt = (half == 0 && wv == 0);

    for (int st = st0; st < st1; ++st) {
        const int d = st / SPP, s = st - d * SPP;
        const int nt = (s < SPP - 1) ? 4 : 3;

        // ---- burst: 8 back-to-back float4s = 512B contiguous per channel stream ----
        // (ts=3 of the tail super-tile overreads into the plane's pad rows: in-bounds, unused)
        const float* fp = fbase + d * FEAT_HW + s * 128 + lq * 8;
        float4 pay[8];
        #pragma unroll
        for (int ts = 0; ts < 4; ++ts) {
            pay[2 * ts]     = *(const float4*)(fp + ts * 32);
            pay[2 * ts + 1] = *(const float4*)(fp + ts * 32 + 4);
        }

        for (int ts = 0; ts < nt; ++ts) {
            const int tp = s * 4 + ts;                  // tile within plane
            const int h  = tp / 3, w0 = (tp - h * 3) * 32;
            const int wq = w0 + lq * 8;
            const int ab = (d * CROP_H + h) * CROP_W + wq;
            int id[8];
            #pragma unroll
            for (int j = 0; j < 8; ++j)
                id[j] = (wq + j < CROP_W) ? atlas[ab + j] : 95;

            union { bf16x8 v; unsigned int u[4]; } A;   // row=l15 ch, k=lq*8+j
            A.u[0] = rne2(pay[2 * ts].x,     pay[2 * ts].y);
            A.u[1] = rne2(pay[2 * ts].z,     pay[2 * ts].w);
            A.u[2] = rne2(pay[2 * ts + 1].x, pay[2 * ts + 1].y);
            A.u[3] = rne2(pay[2 * ts + 1].z, pay[2 * ts + 1].w);

            #pragma unroll
            for (int sb = 0; sb < 6; ++sb) {            // B built per-sb: 4 live regs
                const int seg = sb * 16 + l15;
                union { bf16x8 v; unsigned int u[4]; } B;
                #pragma unroll
                for (int p = 0; p < 4; ++p) {
                    const unsigned int lo = (id[2 * p]     == seg) ? 0x3F80u     : 0u;
                    const unsigned int hi = (id[2 * p + 1] == seg) ? 0x3F800000u : 0u;
                    B.u[p] = lo | hi;
                }
                if (do_cnt)
                    accc[sb] = __builtin_amdgcn_mfma_f32_16x16x32_bf16(ONES.v, B.v, accc[sb], 0, 0, 0);
                acc[sb] = __builtin_amdgcn_mfma_f32_16x16x32_bf16(A.v, B.v, acc[sb], 0, 0, 0);
            }
        }
    }

    // Epilogue: D row = lq*4 + r (local ch within 16), col = l15 (seg). Disjoint rows per wave.
    float* p = part + (use_atomic ? (size_t)half * BIN_SZ : (size_t)bx * BIN_SZ);
    #pragma unroll
    for (int sb = 0; sb < 6; ++sb)
        #pragma unroll
        for (int r = 0; r < 4; ++r) {
            const int i = (wv * 16 + lq * 4 + r) * PSEG + sb * 16 + l15;
            if (use_atomic) unsafeAtomicAdd(&p[i], acc[sb][r]);
            else            p[i] = acc[sb][r];
        }
    if (do_cnt && lq == 0) {                            // counts row (half-0 blocks only)
        #pragma unroll
        for (int sb = 0; sb < 6; ++sb) {
            const int i = 64 * PSEG + sb * 16 + l15;
            if (use_atomic) unsafeAtomicAdd(&p[i], accc[sb][0]);
            else            p[i] = accc[sb][0];
        }
    }
}

// Stage A: 1024 partials -> 16 (8 tile-groups x 2 halves), coalesced across elem.
__global__ __launch_bounds__(256) void reduce_stageA(const float* __restrict__ part,
                                                     float* __restrict__ part2)
{
    const int gi = blockIdx.x * 256 + threadIdx.x;      // [0, BIN_SZ*NCHUNK) exact
    const int k  = gi / BIN_SZ, e = gi - k * BIN_SZ;
    const int g  = k >> 1, half = k & 1;
    const float* p = part + ((size_t)(g * 64) * 2 + half) * BIN_SZ + e;
    float s = 0.0f;
    #pragma unroll 8
    for (int j = 0; j < 64; ++j) s += p[(size_t)j * 2 * BIN_SZ];
    part2[gi] = s;
}

__global__ __launch_bounds__(256) void finalize(const float* __restrict__ src,
                                                float* __restrict__ out,
                                                int fallback)
{
    const int idx = blockIdx.x * 256 + threadIdx.x;
    if (idx >= OUT_N) return;
    const int c   = idx & 63;                           // local channel
    const int s0  = (idx >> 6) % 94;
    const int b   = idx / (94 * 64);                    // batch == channel half
    const int seg = s0 + 1;
    float s = 0.0f, cnt = 0.0f;
    if (fallback) {
        s   = src[(size_t)b * BIN_SZ + c * PSEG + seg];
        cnt = src[64 * PSEG + seg];
    } else {
        #pragma unroll
        for (int g = 0; g < 8; ++g) {
            s   += src[(size_t)(g * 2 + b) * BIN_SZ + c * PSEG + seg];
            cnt += src[(size_t)(g * 2)     * BIN_SZ + 64 * PSEG + seg];
        }
    }
    out[idx] = s / fmaxf(cnt, 1e-6f);
}

extern "C" void kernel_launch(void* const* d_in, const int* in_sizes, int n_in,
                              void* d_out, int out_size, void* d_ws, size_t ws_size,
                              hipStream_t stream)
{
    const float* feat  = (const float*)d_in[0];
    const int*   atlas = (const int*)d_in[1];
    float* out   = (float*)d_out;
    float* part  = (float*)d_ws;
    float* part2 = (float*)((char*)d_ws + PART2_OFF);
    const int use_atomic = (ws_size < WS_NEED) ? 1 : 0;

    if (use_atomic)
        zero_part<<<(2 * BIN_SZ + 255) / 256, 256, 0, stream>>>(part);
    seg_mfma<<<GRID, 256, 0, stream>>>(feat, atlas, part, use_atomic);
    if (!use_atomic)
        reduce_stageA<<<(BIN_SZ * NCHUNK) / 256, 256, 0, stream>>>(part, part2);
    finalize<<<(OUT_N + 255) / 256, 256, 0, stream>>>(use_atomic ? part : part2, out, use_atomic);
}

// Round 12
// 159.006 us; speedup vs baseline: 1.8291x; 1.8291x over previous
//
#include <hip/hip_runtime.h>

// ROI pooling 3D as one-hot MFMA GEMM (transposed): part[ch][seg] = sum_v feat[ch][v] * onehot[v][seg].
// R12 = R11 with the scratch-spill fixed: ts-loop fully unrolled (4 compile-time trips; phantom
// tail tile routes to the trash column), so the 512B burst payload stays in VGPRs.
constexpr int CROP_D  = 91, CROP_H = 109, CROP_W = 91;
constexpr int FEAT_HW = 112 * 96;
constexpr int CSTRIDE = 96 * 112 * 96;                // per-(b,c) elements
constexpr int SPP     = 82;                           // super-tiles per plane (82x4 tiles, last has phantom)
constexpr int NST     = CROP_D * SPP;                 // 7462
constexpr int TPP     = CROP_H * 3;                   // 327 real tiles per plane
constexpr int NCH     = 512;                          // tile-chunks
constexpr int GRID    = NCH * 2;                      // 1024 blocks (x2 channel halves)
constexpr int PSEG    = 96;                           // 95 segs + trash col
constexpr int ROWS    = 65;                           // 64 local ch + counts row
constexpr int BIN_SZ  = ROWS * PSEG;                  // 6240 floats per partial
constexpr int NCHUNK  = 16;                           // 8 tile-groups x 2 halves
constexpr int OUT_N   = 2 * 94 * 64;
constexpr size_t PART2_OFF = (size_t)GRID * BIN_SZ * sizeof(float);
constexpr size_t WS_NEED   = PART2_OFF + (size_t)NCHUNK * BIN_SZ * sizeof(float);

typedef __attribute__((ext_vector_type(8))) short bf16x8;
typedef __attribute__((ext_vector_type(4))) float f32x4;

__device__ inline unsigned int rne2(float a, float b) {   // 2x fp32 -> packed bf16 (RNE)
    unsigned int x = __float_as_uint(a), y = __float_as_uint(b);
    x = (x + 0x7FFFu + ((x >> 16) & 1u)) >> 16;
    y = (y + 0x7FFFu + ((y >> 16) & 1u)) & 0xFFFF0000u;
    return x | y;
}

__global__ __launch_bounds__(256) void zero_part(float* __restrict__ p)   // atomic-fallback only
{
    const int i = blockIdx.x * 256 + threadIdx.x;
    if (i < 2 * BIN_SZ) p[i] = 0.0f;
}

__global__ __launch_bounds__(256, 4) void seg_mfma(const float* __restrict__ feat,
                                                   const int*   __restrict__ atlas,
                                                   float* __restrict__ part,
                                                   int use_atomic)
{
    const int tid = threadIdx.x, wv = tid >> 6, lane = tid & 63;
    const int l15 = lane & 15, lq = lane >> 4;
    const int bx  = blockIdx.x, c = bx >> 1, half = bx & 1;

    f32x4 acc[6], accc[6];                              // 24 + 24 VGPR
    #pragma unroll
    for (int s = 0; s < 6; ++s) {
        acc[s]  = (f32x4){0.f, 0.f, 0.f, 0.f};
        accc[s] = (f32x4){0.f, 0.f, 0.f, 0.f};
    }
    union { bf16x8 v; unsigned int u[4]; } ONES;
    ONES.u[0] = ONES.u[1] = ONES.u[2] = ONES.u[3] = 0x3F803F80u;

    // Contiguous balanced chunk of super-tiles per block pair.
    const int base = NST / NCH, rem = NST % NCH;        // 14, 294
    const int st0  = c * base + (c < rem ? c : rem);
    const int st1  = st0 + base + (c < rem ? 1 : 0);

    const float* fbase = feat + (size_t)(half * 64 + wv * 16 + l15) * CSTRIDE;
    const bool do_cnt = (half == 0 && wv == 0);

    for (int st = st0; st < st1; ++st) {
        const int d = st / SPP, s = st - d * SPP;

        // ---- burst: 8 back-to-back float4s = 512B contiguous per channel stream ----
        // (tail super-tile's vox 96..127 come from the plane's pad rows: in-bounds, trash-routed)
        const float* fp = fbase + d * FEAT_HW + s * 128 + lq * 8;
        float4 pay[8];
        #pragma unroll
        for (int ts = 0; ts < 4; ++ts) {
            pay[2 * ts]     = *(const float4*)(fp + ts * 32);
            pay[2 * ts + 1] = *(const float4*)(fp + ts * 32 + 4);
        }

        #pragma unroll
        for (int ts = 0; ts < 4; ++ts) {                // compile-time: pay stays in VGPRs
            const int tp = s * 4 + ts;                  // tile within plane; 327 = phantom
            const int h  = tp / 3, w0 = (tp - h * 3) * 32;
            const int wq = w0 + lq * 8;
            const int ab = (d * CROP_H + h) * CROP_W + wq;
            const bool real = (tp < TPP);
            int id[8];
            #pragma unroll
            for (int j = 0; j < 8; ++j)
                id[j] = (real && wq + j < CROP_W) ? atlas[ab + j] : 95;

            union { bf16x8 v; unsigned int u[4]; } A;   // row=l15 ch, k=lq*8+j
            A.u[0] = rne2(pay[2 * ts].x,     pay[2 * ts].y);
            A.u[1] = rne2(pay[2 * ts].z,     pay[2 * ts].w);
            A.u[2] = rne2(pay[2 * ts + 1].x, pay[2 * ts + 1].y);
            A.u[3] = rne2(pay[2 * ts + 1].z, pay[2 * ts + 1].w);

            #pragma unroll
            for (int sb = 0; sb < 6; ++sb) {            // B built per-sb: 4 live regs
                const int seg = sb * 16 + l15;
                union { bf16x8 v; unsigned int u[4]; } B;
                #pragma unroll
                for (int p = 0; p < 4; ++p) {
                    const unsigned int lo = (id[2 * p]     == seg) ? 0x3F80u     : 0u;
                    const unsigned int hi = (id[2 * p + 1] == seg) ? 0x3F800000u : 0u;
                    B.u[p] = lo | hi;
                }
                if (do_cnt)
                    accc[sb] = __builtin_amdgcn_mfma_f32_16x16x32_bf16(ONES.v, B.v, accc[sb], 0, 0, 0);
                acc[sb] = __builtin_amdgcn_mfma_f32_16x16x32_bf16(A.v, B.v, acc[sb], 0, 0, 0);
            }
        }
    }

    // Epilogue: D row = lq*4 + r (local ch within 16), col = l15 (seg). Disjoint rows per wave.
    float* p = part + (use_atomic ? (size_t)half * BIN_SZ : (size_t)bx * BIN_SZ);
    #pragma unroll
    for (int sb = 0; sb < 6; ++sb)
        #pragma unroll
        for (int r = 0; r < 4; ++r) {
            const int i = (wv * 16 + lq * 4 + r) * PSEG + sb * 16 + l15;
            if (use_atomic) unsafeAtomicAdd(&p[i], acc[sb][r]);
            else            p[i] = acc[sb][r];
        }
    if (do_cnt && lq == 0) {                            // counts row (half-0 blocks only)
        #pragma unroll
        for (int sb = 0; sb < 6; ++sb) {
            const int i = 64 * PSEG + sb * 16 + l15;
            if (use_atomic) unsafeAtomicAdd(&p[i], accc[sb][0]);
            else            p[i] = accc[sb][0];
        }
    }
}

// Stage A: 1024 partials -> 16 (8 tile-groups x 2 halves), coalesced across elem.
__global__ __launch_bounds__(256) void reduce_stageA(const float* __restrict__ part,
                                                     float* __restrict__ part2)
{
    const int gi = blockIdx.x * 256 + threadIdx.x;      // [0, BIN_SZ*NCHUNK) exact
    const int k  = gi / BIN_SZ, e = gi - k * BIN_SZ;
    const int g  = k >> 1, half = k & 1;
    const float* p = part + ((size_t)(g * 64) * 2 + half) * BIN_SZ + e;
    float s = 0.0f;
    #pragma unroll 8
    for (int j = 0; j < 64; ++j) s += p[(size_t)j * 2 * BIN_SZ];
    part2[gi] = s;
}

__global__ __launch_bounds__(256) void finalize(const float* __restrict__ src,
                                                float* __restrict__ out,
                                                int fallback)
{
    const int idx = blockIdx.x * 256 + threadIdx.x;
    if (idx >= OUT_N) return;
    const int c   = idx & 63;                           // local channel
    const int s0  = (idx >> 6) % 94;
    const int b   = idx / (94 * 64);                    // batch == channel half
    const int seg = s0 + 1;
    float s = 0.0f, cnt = 0.0f;
    if (fallback) {
        s   = src[(size_t)b * BIN_SZ + c * PSEG + seg];
        cnt = src[64 * PSEG + seg];
    } else {
        #pragma unroll
        for (int g = 0; g < 8; ++g) {
            s   += src[(size_t)(g * 2 + b) * BIN_SZ + c * PSEG + seg];
            cnt += src[(size_t)(g * 2)     * BIN_SZ + 64 * PSEG + seg];
        }
    }
    out[idx] = s / fmaxf(cnt, 1e-6f);
}

extern "C" void kernel_launch(void* const* d_in, const int* in_sizes, int n_in,
                              void* d_out, int out_size, void* d_ws, size_t ws_size,
                              hipStream_t stream)
{
    const float* feat  = (const float*)d_in[0];
    const int*   atlas = (const int*)d_in[1];
    float* out   = (float*)d_out;
    float* part  = (float*)d_ws;
    float* part2 = (float*)((char*)d_ws + PART2_OFF);
    const int use_atomic = (ws_size < WS_NEED) ? 1 : 0;

    if (use_atomic)
        zero_part<<<(2 * BIN_SZ + 255) / 256, 256, 0, stream>>>(part);
    seg_mfma<<<GRID, 256, 0, stream>>>(feat, atlas, part, use_atomic);
    if (!use_atomic)
        reduce_stageA<<<(BIN_SZ * NCHUNK) / 256, 256, 0, stream>>>(part, part2);
    finalize<<<(OUT_N + 255) / 256, 256, 0, stream>>>(use_atomic ? part : part2, out, use_atomic);
}